// Round 11
// baseline (193.736 us; speedup 1.0000x reference)
//
#include <hip/hip_runtime.h>
#include <math.h>

#define S_LEN  2048
#define BATCH  2
#define DM     1024
#define NHEAD  16
#define DHEAD  64
#define WIN    256
#define MROWS  4096

#define KP   72     // bf16 LDS row stride for attn K/V tiles
#define PPAD 68     // f32 LDS row stride for attn P

typedef __attribute__((ext_vector_type(8))) short bf16x8;
typedef __attribute__((ext_vector_type(4))) float f32x4;

__device__ __forceinline__ unsigned short f2b(float f) {   // RNE
    unsigned int u = __float_as_uint(f);
    return (unsigned short)((u + 0x7fffu + ((u >> 16) & 1u)) >> 16);
}
__device__ __forceinline__ void gld16(const void* g, void* l) {
    __builtin_amdgcn_global_load_lds(
        (const __attribute__((address_space(1))) void*)g,
        (__attribute__((address_space(3))) void*)l, 16, 0, 0);
}
__device__ __forceinline__ bf16x8 pack8(float4 a, float4 b) {
    bf16x8 r;
    r[0] = (short)f2b(a.x); r[1] = (short)f2b(a.y);
    r[2] = (short)f2b(a.z); r[3] = (short)f2b(a.w);
    r[4] = (short)f2b(b.x); r[5] = (short)f2b(b.y);
    r[6] = (short)f2b(b.z); r[7] = (short)f2b(b.w);
    return r;
}

// ---------------------------------------------------------------------------
// fp32 -> bf16 convert (x): 4M elems, 4/thread
// ---------------------------------------------------------------------------
__global__ __launch_bounds__(256)
void cvtx(const float* __restrict__ x, unsigned short* __restrict__ xb)
{
    const int i = (blockIdx.x * 256 + threadIdx.x) * 4;
    float4 f = *(const float4*)(x + i);
    ushort4 o; o.x = f2b(f.x); o.y = f2b(f.y); o.z = f2b(f.z); o.w = f2b(f.w);
    *(ushort4*)(xb + i) = o;
}

// ---------------------------------------------------------------------------
// 4x fused: W (K x N fp32) -> W^T (N x K bf16)
// ---------------------------------------------------------------------------
__global__ __launch_bounds__(256)
void twcvt4(const float* __restrict__ W0, const float* __restrict__ W1,
            const float* __restrict__ W2, const float* __restrict__ W3,
            unsigned short* __restrict__ T0, unsigned short* __restrict__ T1,
            unsigned short* __restrict__ T2, unsigned short* __restrict__ T3)
{
    const int zz = blockIdx.z;
    const float* W = (zz == 0) ? W0 : (zz == 1) ? W1 : (zz == 2) ? W2 : W3;
    unsigned short* WT = (zz == 0) ? T0 : (zz == 1) ? T1 : (zz == 2) ? T2 : T3;

    __shared__ float t32[32][33];
    const int bx = blockIdx.x * 32;
    const int by = blockIdx.y * 32;
    const int c  = threadIdx.x & 31;
    const int r0 = threadIdx.x >> 5;
#pragma unroll
    for (int p = 0; p < 4; ++p)
        t32[r0 + 8 * p][c] = W[(size_t)(by + r0 + 8 * p) * DM + bx + c];
    __syncthreads();
#pragma unroll
    for (int p = 0; p < 4; ++p)
        WT[(size_t)(bx + r0 + 8 * p) * DM + by + c] = f2b(t32[c][r0 + 8 * p]);
}

// ---------------------------------------------------------------------------
// Fused QKV bf16 MFMA GEMM, 128x128 tile, BK=64 (16 ksteps -> half the
// barriers of BK=32), 4 waves (2x2 of 64x64), 32 MFMA + 16 ds_read_b128 +
// 8 gld16 per wave-kstep. LDS 32 KB.
// XOR swizzle: storage[row][cg] = logical[row][cg ^ (row&7)] (8-group key:
// row stride 128 B == 0 mod 32 banks, so the key alone must decorrelate;
// per-16-lane phase -> 2 lanes/column-group = free).
//   D[row][col] = sum_k A[row][k] * BT[col][k]
// sec = colBase>>10: 0: q scaled 0.125*exp(-beta[h]) -> (z,s,dh)
//                    1: k -> (z,s,dh)
//                    2: v -> TRANSPOSED (z,dh,s), paired-u32 stores
// ---------------------------------------------------------------------------
__global__ __launch_bounds__(256)
void gemm_qkv(const unsigned short* __restrict__ A,
              const unsigned short* __restrict__ BT,
              const float* __restrict__ b0,
              const float* __restrict__ b1,
              const float* __restrict__ b2,
              const float* __restrict__ beta,
              unsigned short* __restrict__ Cb)
{
    __shared__ unsigned short As[128 * 64];   // 16 KB
    __shared__ unsigned short Bs[128 * 64];   // 16 KB

    const int t  = threadIdx.x;
    const int wv = t >> 6, ln = t & 63;
    const int rowBase = blockIdx.y * 128;
    const int colBase = blockIdx.x * 128;

    const int m16 = ln & 15, g = ln >> 4;
    const int wr = wv >> 1, wc = wv & 1;
    const int key = m16 & 7;                  // key(row) = row & 7

    const int lr8 = ln >> 3;                  // staging row within 8-row group
    const int lq8 = (ln & 7) ^ lr8;           // swizzled source column group
    const unsigned short* ga = A  + (size_t)(rowBase + wv * 32 + lr8) * DM + lq8 * 8;
    const unsigned short* gb = BT + (size_t)(colBase + wv * 32 + lr8) * DM + lq8 * 8;

    f32x4 acc[4][4];
#pragma unroll
    for (int u = 0; u < 4; ++u)
#pragma unroll
        for (int v = 0; v < 4; ++v)
            acc[u][v] = (f32x4){0.f, 0.f, 0.f, 0.f};

    for (int kb = 0; kb < DM; kb += 64) {
#pragma unroll
        for (int i = 0; i < 4; ++i) {
            gld16(ga + (size_t)(i * 8) * DM + kb, As + (wv * 32 + i * 8) * 64);
            gld16(gb + (size_t)(i * 8) * DM + kb, Bs + (wv * 32 + i * 8) * 64);
        }
        __syncthreads();

        bf16x8 af[4], bfr[4];
        // k-half 0: logical column group g -> storage (g ^ key)
#pragma unroll
        for (int u = 0; u < 4; ++u)
            af[u] = *(const bf16x8*)&As[(wr * 64 + u * 16 + m16) * 64 + ((g ^ key) * 8)];
#pragma unroll
        for (int v = 0; v < 4; ++v)
            bfr[v] = *(const bf16x8*)&Bs[(wc * 64 + v * 16 + m16) * 64 + ((g ^ key) * 8)];
#pragma unroll
        for (int u = 0; u < 4; ++u)
#pragma unroll
            for (int v = 0; v < 4; ++v)
                acc[u][v] = __builtin_amdgcn_mfma_f32_16x16x32_bf16(
                    af[u], bfr[v], acc[u][v], 0, 0, 0);
        // k-half 1: logical column group 4+g
#pragma unroll
        for (int u = 0; u < 4; ++u)
            af[u] = *(const bf16x8*)&As[(wr * 64 + u * 16 + m16) * 64 + (((4 + g) ^ key) * 8)];
#pragma unroll
        for (int v = 0; v < 4; ++v)
            bfr[v] = *(const bf16x8*)&Bs[(wc * 64 + v * 16 + m16) * 64 + (((4 + g) ^ key) * 8)];
#pragma unroll
        for (int u = 0; u < 4; ++u)
#pragma unroll
            for (int v = 0; v < 4; ++v)
                acc[u][v] = __builtin_amdgcn_mfma_f32_16x16x32_bf16(
                    af[u], bfr[v], acc[u][v], 0, 0, 0);
        __syncthreads();
    }

    const int q4 = g * 4;
    const int sec = colBase >> 10;        // block-uniform: 0=q 1=k 2=v
    if (sec < 2) {
#pragma unroll
        for (int v = 0; v < 4; ++v) {
            const int col = colBase + wc * 64 + v * 16 + m16;
            const int h   = (col >> 6) & (NHEAD - 1);
            const int dh  = col & 63;
            const float bi = (sec == 0 ? b0 : b1)[col & (DM - 1)];
            const float sc = (sec == 0) ? 0.125f * __expf(-beta[h]) : 1.0f;
            unsigned short* base = Cb + (size_t)sec * MROWS * DM;
#pragma unroll
            for (int u = 0; u < 4; ++u)
#pragma unroll
                for (int r = 0; r < 4; ++r) {
                    const int row = rowBase + wr * 64 + u * 16 + q4 + r;
                    const int s = row >> 1, bb = row & 1;
                    const int z = bb * NHEAD + h;
                    base[((size_t)z * S_LEN + s) * DHEAD + dh] =
                        f2b((acc[u][v][r] + bi) * sc);
                }
        }
    } else {
        // v, written transposed to vt(z,dh,s). row0 % 4 == 0 -> s0 even.
        unsigned short* vtb = Cb + (size_t)2 * MROWS * DM;
#pragma unroll
        for (int v = 0; v < 4; ++v) {
            const int col = colBase + wc * 64 + v * 16 + m16;
            const int h   = (col >> 6) & (NHEAD - 1);
            const int dh  = col & 63;
            const float bi = b2[col & (DM - 1)];
#pragma unroll
            for (int u = 0; u < 4; ++u) {
                const int row0 = rowBase + wr * 64 + u * 16 + q4;
                const int s0   = row0 >> 1;
                ushort2 p0, p1;
                p0.x = f2b(acc[u][v][0] + bi);   // bb=0, s0
                p0.y = f2b(acc[u][v][2] + bi);   // bb=0, s0+1
                p1.x = f2b(acc[u][v][1] + bi);   // bb=1, s0
                p1.y = f2b(acc[u][v][3] + bi);   // bb=1, s0+1
                *(ushort2*)(vtb + ((size_t)(h * DHEAD + dh) * S_LEN + s0)) = p0;
                *(ushort2*)(vtb + ((size_t)((NHEAD + h) * DHEAD + dh) * S_LEN + s0)) = p1;
            }
        }
    }
}

// ---------------------------------------------------------------------------
// Output projection: 128x64 tile, BK=32 (R10-proven), 4 waves 2x2 of 64x32.
// ---------------------------------------------------------------------------
__global__ __launch_bounds__(256)
void gemm_out(const unsigned short* __restrict__ A,
              const unsigned short* __restrict__ BT,
              const float* __restrict__ bias,
              float* __restrict__ Cf)
{
    __shared__ unsigned short As[128 * 32];   // 8 KB
    __shared__ unsigned short Bs[64 * 32];    // 4 KB

    const int t  = threadIdx.x;
    const int wv = t >> 6, ln = t & 63;
    const int rowBase = blockIdx.y * 128;
    const int colBase = blockIdx.x * 64;

    const int m16 = ln & 15, g = ln >> 4;
    const int wr = wv >> 1, wc = wv & 1;
    const int swz = (m16 >> 1) & 3;

    const int lr = ln >> 2;
    const int lq = (ln & 3) ^ ((lr >> 1) & 3);
    const unsigned short* ga = A  + (size_t)(rowBase + wv * 16 + lr) * DM + lq * 8;
    const unsigned short* gb = BT + (size_t)(colBase + wv * 16 + lr) * DM + lq * 8;
    unsigned short* la0 = As + wv * 512;
    unsigned short* la1 = la0 + 2048;         // rows 64..127
    unsigned short* lb  = Bs + wv * 512;      // 64 rows total

    f32x4 acc[4][2];
#pragma unroll
    for (int u = 0; u < 4; ++u)
#pragma unroll
        for (int v = 0; v < 2; ++v)
            acc[u][v] = (f32x4){0.f, 0.f, 0.f, 0.f};

    for (int kb = 0; kb < DM; kb += 32) {
        gld16(ga + kb, la0);
        gld16(ga + (size_t)64 * DM + kb, la1);
        gld16(gb + kb, lb);
        __syncthreads();

        bf16x8 af[4], bfr[2];
#pragma unroll
        for (int u = 0; u < 4; ++u)
            af[u] = *(const bf16x8*)&As[(wr * 64 + u * 16 + m16) * 32 + ((g ^ swz) * 8)];
#pragma unroll
        for (int v = 0; v < 2; ++v)
            bfr[v] = *(const bf16x8*)&Bs[(wc * 32 + v * 16 + m16) * 32 + ((g ^ swz) * 8)];
#pragma unroll
        for (int u = 0; u < 4; ++u)
#pragma unroll
            for (int v = 0; v < 2; ++v)
                acc[u][v] = __builtin_amdgcn_mfma_f32_16x16x32_bf16(
                    af[u], bfr[v], acc[u][v], 0, 0, 0);
        __syncthreads();
    }

    const int q4 = g * 4;
#pragma unroll
    for (int v = 0; v < 2; ++v) {
        const int col = colBase + wc * 32 + v * 16 + m16;
        const float bi = bias[col];
#pragma unroll
        for (int u = 0; u < 4; ++u)
#pragma unroll
            for (int r = 0; r < 4; ++r) {
                const int row = rowBase + wr * 64 + u * 16 + q4 + r;
                Cf[(size_t)row * DM + col] = acc[u][v][r] + bi;
            }
    }
}

// ---------------------------------------------------------------------------
// MFMA flash attention, windowed causal + sink — NO online max.
// Scores are bounded (|s| <~ 6: q pre-scaled by 0.125*exp(-beta)), so plain
// exp(s) is safe in fp32 (overflow at 88). Sink handled by l0 = 1 = exp(0).
// Masked entries: exp(-1e30) == 0 exactly. Removes the max shuffle-reduce,
// alpha, and O rescale per chunk. Final normalize by 1/l.
// q,k in (z,s,dh); V pre-transposed vt (z,dh,s). All staging b128.
// ---------------------------------------------------------------------------
__global__ __launch_bounds__(256, 4)
void attn_mfma(const unsigned short* __restrict__ q,
               const unsigned short* __restrict__ k,
               const unsigned short* __restrict__ vt,
               unsigned short* __restrict__ ao)
{
    __shared__ unsigned short Ks[64 * KP];   // [key][d]
    __shared__ unsigned short Vs[64 * KP];   // [dh][key]
    __shared__ float Ps[64][PPAD];           // [wave*16 + qrow][key]

    const int t   = threadIdx.x;
    const int wv  = t >> 6, ln = t & 63;
    const int m16 = ln & 15, g = ln >> 4;
    const int z   = blockIdx.y;
    const int q0  = blockIdx.x * 64;
    const size_t zbase = (size_t)z * S_LEN * DHEAD;

    const unsigned short* qrow = q + zbase + (size_t)(q0 + wv * 16 + m16) * DHEAD;
    bf16x8 qf0 = *(const bf16x8*)(qrow + g * 8);
    bf16x8 qf1 = *(const bf16x8*)(qrow + 32 + g * 8);

    f32x4 oacc[4];
#pragma unroll
    for (int v4 = 0; v4 < 4; ++v4) oacc[v4] = (f32x4){0.f, 0.f, 0.f, 0.f};
    float lr[4];
#pragma unroll
    for (int r = 0; r < 4; ++r) lr[r] = 1.f;   // sink: exp(0)

    for (int c = 0; c < 5; ++c) {
        const int kb = q0 - 256 + c * 64;
        if (kb < 0) continue;
        __syncthreads();

        // stage K [64][64] and V^T [64][64], b128 copies
#pragma unroll
        for (int i = 0; i < 2; ++i) {
            const int id  = t + 256 * i;
            const int row = id >> 3;
            const int co  = (id & 7) * 8;
            *(bf16x8*)&Ks[row * KP + co] =
                *(const bf16x8*)(k + zbase + (size_t)(kb + row) * DHEAD + co);
            *(bf16x8*)&Vs[row * KP + co] =
                *(const bf16x8*)(vt + ((size_t)z * DHEAD + row) * S_LEN + kb + co);
        }
        __syncthreads();

        // S = Q K^T
        f32x4 sacc[4];
#pragma unroll
        for (int v4 = 0; v4 < 4; ++v4) {
            sacc[v4] = (f32x4){0.f, 0.f, 0.f, 0.f};
            bf16x8 kf0 = *(const bf16x8*)&Ks[(v4 * 16 + m16) * KP + g * 8];
            sacc[v4] = __builtin_amdgcn_mfma_f32_16x16x32_bf16(qf0, kf0, sacc[v4], 0, 0, 0);
            bf16x8 kf1 = *(const bf16x8*)&Ks[(v4 * 16 + m16) * KP + 32 + g * 8];
            sacc[v4] = __builtin_amdgcn_mfma_f32_16x16x32_bf16(qf1, kf1, sacc[v4], 0, 0, 0);
        }

        // mask + exp + row-sum (no max): P -> LDS
        const bool mhi = (c == 4), mlo = (c == 0);
#pragma unroll
        for (int r = 0; r < 4; ++r) {
            const int ig = q0 + wv * 16 + g * 4 + r;
            float rsum = 0.f;
#pragma unroll
            for (int v4 = 0; v4 < 4; ++v4) {
                const int jg = kb + v4 * 16 + m16;
                float x = sacc[v4][r];
                const bool valid = (!mhi || jg <= ig) && (!mlo || jg >= ig - (WIN - 1));
                x = valid ? x : -1e30f;
                const float pp = __expf(x);     // masked -> exactly 0
                Ps[wv * 16 + g * 4 + r][v4 * 16 + m16] = pp;
                rsum += pp;
            }
#pragma unroll
            for (int off = 1; off < 16; off <<= 1)
                rsum += __shfl_xor(rsum, off, 64);
            lr[r] += rsum;
        }
        __syncthreads();

        // O += P V
        const float* prow = &Ps[wv * 16 + m16][0];
        bf16x8 pf0 = pack8(*(const float4*)(prow + g * 8),
                           *(const float4*)(prow + g * 8 + 4));
        bf16x8 pf1 = pack8(*(const float4*)(prow + 32 + g * 8),
                           *(const float4*)(prow + 32 + g * 8 + 4));
#pragma unroll
        for (int v4 = 0; v4 < 4; ++v4) {
            bf16x8 vf0 = *(const bf16x8*)&Vs[(v4 * 16 + m16) * KP + g * 8];
            oacc[v4] = __builtin_amdgcn_mfma_f32_16x16x32_bf16(pf0, vf0, oacc[v4], 0, 0, 0);
            bf16x8 vf1 = *(const bf16x8*)&Vs[(v4 * 16 + m16) * KP + 32 + g * 8];
            oacc[v4] = __builtin_amdgcn_mfma_f32_16x16x32_bf16(pf1, vf1, oacc[v4], 0, 0, 0);
        }
    }

    const int bb = z >> 4, h = z & 15;
#pragma unroll
    for (int r = 0; r < 4; ++r) {
        const int ig  = q0 + wv * 16 + g * 4 + r;
        const float inv = 1.f / lr[r];
#pragma unroll
        for (int v4 = 0; v4 < 4; ++v4)
            ao[(size_t)(ig * BATCH + bb) * DM + h * DHEAD + v4 * 16 + m16] =
                f2b(oacc[v4][r] * inv);
    }
}

// ---------------------------------------------------------------------------
extern "C" void kernel_launch(void* const* d_in, const int* in_sizes, int n_in,
                              void* d_out, int out_size, void* d_ws, size_t ws_size,
                              hipStream_t stream)
{
    const float* x    = (const float*)d_in[0];
    const float* beta = (const float*)d_in[1];
    const float* Wq   = (const float*)d_in[2];
    const float* bq   = (const float*)d_in[3];
    const float* Wk   = (const float*)d_in[4];
    const float* bk   = (const float*)d_in[5];
    const float* Wv   = (const float*)d_in[6];
    const float* bv   = (const float*)d_in[7];
    const float* Wo   = (const float*)d_in[8];
    const float* bo   = (const float*)d_in[9];
    float* out = (float*)d_out;

    unsigned short* w = (unsigned short*)d_ws;
    const size_t seg = (size_t)MROWS * DM;      // 4M elems
    unsigned short* qb  = w;                    // q (z,s,dh)
    unsigned short* kb  = w + seg;              // k (z,s,dh)
    unsigned short* vtb = w + 2 * seg;          // v^T (z,dh,s) -- direct from QKV
    unsigned short* ab  = w + 3 * seg;          // attn out, row-major
    unsigned short* xb  = w + 4 * seg;          // x bf16
    unsigned short* wtq = w + 5 * seg;          // WqT|WkT|WvT|WoT contiguous
    unsigned short* wtk = wtq + (size_t)DM * DM;
    unsigned short* wtv = wtk + (size_t)DM * DM;
    unsigned short* wto = wtv + (size_t)DM * DM;

    cvtx<<<4096, 256, 0, stream>>>(x, xb);
    twcvt4<<<dim3(32, 32, 4), 256, 0, stream>>>(Wq, Wk, Wv, Wo, wtq, wtk, wtv, wto);

    // fused Q+K+V projection: N=3072, V written pre-transposed (768 blocks)
    gemm_qkv<<<dim3(3072 / 128, MROWS / 128), 256, 0, stream>>>(
        xb, wtq, bq, bk, bv, beta, qb);

    attn_mfma<<<dim3(S_LEN / 64, BATCH * NHEAD), 256, 0, stream>>>(qb, kb, vtb, ab);

    // output projection: 128x64 tiles -> 512 blocks (2/CU)
    gemm_out<<<dim3(DM / 64, MROWS / 128), 256, 0, stream>>>(ab, wto, bo, out);
}

// Round 12
// 185.698 us; speedup vs baseline: 1.0433x; 1.0433x over previous
//
#include <hip/hip_runtime.h>
#include <math.h>

#define S_LEN  2048
#define BATCH  2
#define DM     1024
#define NHEAD  16
#define DHEAD  64
#define WIN    256
#define MROWS  4096

#define KP   72     // bf16 LDS row stride for attn K/V tiles
#define PPAD 68     // f32 LDS row stride for attn P

typedef __attribute__((ext_vector_type(8))) short bf16x8;
typedef __attribute__((ext_vector_type(4))) float f32x4;

__device__ __forceinline__ unsigned short f2b(float f) {   // RNE
    unsigned int u = __float_as_uint(f);
    return (unsigned short)((u + 0x7fffu + ((u >> 16) & 1u)) >> 16);
}
__device__ __forceinline__ void gld16(const void* g, void* l) {
    __builtin_amdgcn_global_load_lds(
        (const __attribute__((address_space(1))) void*)g,
        (__attribute__((address_space(3))) void*)l, 16, 0, 0);
}
__device__ __forceinline__ bf16x8 pack8(float4 a, float4 b) {
    bf16x8 r;
    r[0] = (short)f2b(a.x); r[1] = (short)f2b(a.y);
    r[2] = (short)f2b(a.z); r[3] = (short)f2b(a.w);
    r[4] = (short)f2b(b.x); r[5] = (short)f2b(b.y);
    r[6] = (short)f2b(b.z); r[7] = (short)f2b(b.w);
    return r;
}

// ---------------------------------------------------------------------------
// fp32 -> bf16 convert (x): 4M elems, 4/thread
// ---------------------------------------------------------------------------
__global__ __launch_bounds__(256)
void cvtx(const float* __restrict__ x, unsigned short* __restrict__ xb)
{
    const int i = (blockIdx.x * 256 + threadIdx.x) * 4;
    float4 f = *(const float4*)(x + i);
    ushort4 o; o.x = f2b(f.x); o.y = f2b(f.y); o.z = f2b(f.z); o.w = f2b(f.w);
    *(ushort4*)(xb + i) = o;
}

// ---------------------------------------------------------------------------
// 4x fused: W (K x N fp32) -> W^T (N x K bf16)
// ---------------------------------------------------------------------------
__global__ __launch_bounds__(256)
void twcvt4(const float* __restrict__ W0, const float* __restrict__ W1,
            const float* __restrict__ W2, const float* __restrict__ W3,
            unsigned short* __restrict__ T0, unsigned short* __restrict__ T1,
            unsigned short* __restrict__ T2, unsigned short* __restrict__ T3)
{
    const int zz = blockIdx.z;
    const float* W = (zz == 0) ? W0 : (zz == 1) ? W1 : (zz == 2) ? W2 : W3;
    unsigned short* WT = (zz == 0) ? T0 : (zz == 1) ? T1 : (zz == 2) ? T2 : T3;

    __shared__ float t32[32][33];
    const int bx = blockIdx.x * 32;
    const int by = blockIdx.y * 32;
    const int c  = threadIdx.x & 31;
    const int r0 = threadIdx.x >> 5;
#pragma unroll
    for (int p = 0; p < 4; ++p)
        t32[r0 + 8 * p][c] = W[(size_t)(by + r0 + 8 * p) * DM + bx + c];
    __syncthreads();
#pragma unroll
    for (int p = 0; p < 4; ++p)
        WT[(size_t)(bx + r0 + 8 * p) * DM + by + c] = f2b(t32[c][r0 + 8 * p]);
}

// ---------------------------------------------------------------------------
// Fused QKV bf16 MFMA GEMM (R10-proven best: 56.5 us): 128x128 tile, BK=32,
// 4 waves (2x2 of 64x64), 16 MFMA + 8 ds_read_b128 per wave-kstep.
// XOR k-group swizzle key=(row>>1)&3 -> SQ_LDS_BANK_CONFLICT = 0 (R9).
//   D[row][col] = sum_k A[row][k] * BT[col][k]
// sec = colBase>>10: 0: q scaled 0.125*exp(-beta[h]) -> (z,s,dh)
//                    1: k -> (z,s,dh)
//                    2: v -> TRANSPOSED (z,dh,s), paired-u32 stores
// ---------------------------------------------------------------------------
__global__ __launch_bounds__(256)
void gemm_qkv(const unsigned short* __restrict__ A,
              const unsigned short* __restrict__ BT,
              const float* __restrict__ b0,
              const float* __restrict__ b1,
              const float* __restrict__ b2,
              const float* __restrict__ beta,
              unsigned short* __restrict__ Cb)
{
    __shared__ unsigned short As[128 * 32];   // 8 KB
    __shared__ unsigned short Bs[128 * 32];   // 8 KB

    const int t  = threadIdx.x;
    const int wv = t >> 6, ln = t & 63;
    const int rowBase = blockIdx.y * 128;
    const int colBase = blockIdx.x * 128;

    const int m16 = ln & 15, g = ln >> 4;
    const int wr = wv >> 1, wc = wv & 1;
    const int swz = (m16 >> 1) & 3;           // key(row) = (row>>1)&3

    const int lr = ln >> 2;
    const int lq = (ln & 3) ^ ((lr >> 1) & 3);
    const unsigned short* ga = A  + (size_t)(rowBase + wv * 16 + lr) * DM + lq * 8;
    const unsigned short* gb = BT + (size_t)(colBase + wv * 16 + lr) * DM + lq * 8;
    unsigned short* la0 = As + wv * 512;
    unsigned short* la1 = la0 + 2048;
    unsigned short* lb0 = Bs + wv * 512;
    unsigned short* lb1 = lb0 + 2048;

    f32x4 acc[4][4];
#pragma unroll
    for (int u = 0; u < 4; ++u)
#pragma unroll
        for (int v = 0; v < 4; ++v)
            acc[u][v] = (f32x4){0.f, 0.f, 0.f, 0.f};

    for (int kb = 0; kb < DM; kb += 32) {
        gld16(ga + kb, la0);
        gld16(ga + (size_t)64 * DM + kb, la1);
        gld16(gb + kb, lb0);
        gld16(gb + (size_t)64 * DM + kb, lb1);
        __syncthreads();

        bf16x8 af[4], bfr[4];
#pragma unroll
        for (int u = 0; u < 4; ++u)
            af[u] = *(const bf16x8*)&As[(wr * 64 + u * 16 + m16) * 32 + ((g ^ swz) * 8)];
#pragma unroll
        for (int v = 0; v < 4; ++v)
            bfr[v] = *(const bf16x8*)&Bs[(wc * 64 + v * 16 + m16) * 32 + ((g ^ swz) * 8)];
#pragma unroll
        for (int u = 0; u < 4; ++u)
#pragma unroll
            for (int v = 0; v < 4; ++v)
                acc[u][v] = __builtin_amdgcn_mfma_f32_16x16x32_bf16(
                    af[u], bfr[v], acc[u][v], 0, 0, 0);
        __syncthreads();
    }

    const int q4 = g * 4;
    const int sec = colBase >> 10;        // block-uniform: 0=q 1=k 2=v
    if (sec < 2) {
#pragma unroll
        for (int v = 0; v < 4; ++v) {
            const int col = colBase + wc * 64 + v * 16 + m16;
            const int h   = (col >> 6) & (NHEAD - 1);
            const int dh  = col & 63;
            const float bi = (sec == 0 ? b0 : b1)[col & (DM - 1)];
            const float sc = (sec == 0) ? 0.125f * __expf(-beta[h]) : 1.0f;
            unsigned short* base = Cb + (size_t)sec * MROWS * DM;
#pragma unroll
            for (int u = 0; u < 4; ++u)
#pragma unroll
                for (int r = 0; r < 4; ++r) {
                    const int row = rowBase + wr * 64 + u * 16 + q4 + r;
                    const int s = row >> 1, bb = row & 1;
                    const int z = bb * NHEAD + h;
                    base[((size_t)z * S_LEN + s) * DHEAD + dh] =
                        f2b((acc[u][v][r] + bi) * sc);
                }
        }
    } else {
        // v, written transposed to vt(z,dh,s). row0 % 4 == 0 -> s0 even,
        // rows (r=0,2)->bb=0 at s0,s0+1 ; (r=1,3)->bb=1 at s0,s0+1.
        unsigned short* vtb = Cb + (size_t)2 * MROWS * DM;
#pragma unroll
        for (int v = 0; v < 4; ++v) {
            const int col = colBase + wc * 64 + v * 16 + m16;
            const int h   = (col >> 6) & (NHEAD - 1);
            const int dh  = col & 63;
            const float bi = b2[col & (DM - 1)];
#pragma unroll
            for (int u = 0; u < 4; ++u) {
                const int row0 = rowBase + wr * 64 + u * 16 + q4;
                const int s0   = row0 >> 1;
                ushort2 p0, p1;
                p0.x = f2b(acc[u][v][0] + bi);   // bb=0, s0
                p0.y = f2b(acc[u][v][2] + bi);   // bb=0, s0+1
                p1.x = f2b(acc[u][v][1] + bi);   // bb=1, s0
                p1.y = f2b(acc[u][v][3] + bi);   // bb=1, s0+1
                *(ushort2*)(vtb + ((size_t)(h * DHEAD + dh) * S_LEN + s0)) = p0;
                *(ushort2*)(vtb + ((size_t)((NHEAD + h) * DHEAD + dh) * S_LEN + s0)) = p1;
            }
        }
    }
}

// ---------------------------------------------------------------------------
// Output projection: 128x64 tile (512 blocks = 2/CU), BK=32, 4 waves
// as 2x2 of 64x32 (R10-proven).
// ---------------------------------------------------------------------------
__global__ __launch_bounds__(256)
void gemm_out(const unsigned short* __restrict__ A,
              const unsigned short* __restrict__ BT,
              const float* __restrict__ bias,
              float* __restrict__ Cf)
{
    __shared__ unsigned short As[128 * 32];   // 8 KB
    __shared__ unsigned short Bs[64 * 32];    // 4 KB

    const int t  = threadIdx.x;
    const int wv = t >> 6, ln = t & 63;
    const int rowBase = blockIdx.y * 128;
    const int colBase = blockIdx.x * 64;

    const int m16 = ln & 15, g = ln >> 4;
    const int wr = wv >> 1, wc = wv & 1;
    const int swz = (m16 >> 1) & 3;

    const int lr = ln >> 2;
    const int lq = (ln & 3) ^ ((lr >> 1) & 3);
    const unsigned short* ga = A  + (size_t)(rowBase + wv * 16 + lr) * DM + lq * 8;
    const unsigned short* gb = BT + (size_t)(colBase + wv * 16 + lr) * DM + lq * 8;
    unsigned short* la0 = As + wv * 512;
    unsigned short* la1 = la0 + 2048;         // rows 64..127
    unsigned short* lb  = Bs + wv * 512;      // 64 rows total

    f32x4 acc[4][2];
#pragma unroll
    for (int u = 0; u < 4; ++u)
#pragma unroll
        for (int v = 0; v < 2; ++v)
            acc[u][v] = (f32x4){0.f, 0.f, 0.f, 0.f};

    for (int kb = 0; kb < DM; kb += 32) {
        gld16(ga + kb, la0);
        gld16(ga + (size_t)64 * DM + kb, la1);
        gld16(gb + kb, lb);
        __syncthreads();

        bf16x8 af[4], bfr[2];
#pragma unroll
        for (int u = 0; u < 4; ++u)
            af[u] = *(const bf16x8*)&As[(wr * 64 + u * 16 + m16) * 32 + ((g ^ swz) * 8)];
#pragma unroll
        for (int v = 0; v < 2; ++v)
            bfr[v] = *(const bf16x8*)&Bs[(wc * 32 + v * 16 + m16) * 32 + ((g ^ swz) * 8)];
#pragma unroll
        for (int u = 0; u < 4; ++u)
#pragma unroll
            for (int v = 0; v < 2; ++v)
                acc[u][v] = __builtin_amdgcn_mfma_f32_16x16x32_bf16(
                    af[u], bfr[v], acc[u][v], 0, 0, 0);
        __syncthreads();
    }

    const int q4 = g * 4;
#pragma unroll
    for (int v = 0; v < 2; ++v) {
        const int col = colBase + wc * 32 + v * 16 + m16;
        const float bi = bias[col];
#pragma unroll
        for (int u = 0; u < 4; ++u)
#pragma unroll
            for (int r = 0; r < 4; ++r) {
                const int row = rowBase + wr * 64 + u * 16 + q4 + r;
                Cf[(size_t)row * DM + col] = acc[u][v][r] + bi;
            }
    }
}

// ---------------------------------------------------------------------------
// MFMA flash attention, windowed causal + sink — NO online max (R11-proven).
// Scores bounded (|s| <~ 6 after 0.125*exp(-beta) pre-scale) -> plain exp
// is safe in fp32. Sink: l0 = 1 = exp(0). Masked: exp(-1e30) == 0.
// q,k in (z,s,dh); V pre-transposed vt (z,dh,s). All staging b128.
// ---------------------------------------------------------------------------
__global__ __launch_bounds__(256, 4)
void attn_mfma(const unsigned short* __restrict__ q,
               const unsigned short* __restrict__ k,
               const unsigned short* __restrict__ vt,
               unsigned short* __restrict__ ao)
{
    __shared__ unsigned short Ks[64 * KP];   // [key][d]
    __shared__ unsigned short Vs[64 * KP];   // [dh][key]
    __shared__ float Ps[64][PPAD];           // [wave*16 + qrow][key]

    const int t   = threadIdx.x;
    const int wv  = t >> 6, ln = t & 63;
    const int m16 = ln & 15, g = ln >> 4;
    const int z   = blockIdx.y;
    const int q0  = blockIdx.x * 64;
    const size_t zbase = (size_t)z * S_LEN * DHEAD;

    const unsigned short* qrow = q + zbase + (size_t)(q0 + wv * 16 + m16) * DHEAD;
    bf16x8 qf0 = *(const bf16x8*)(qrow + g * 8);
    bf16x8 qf1 = *(const bf16x8*)(qrow + 32 + g * 8);

    f32x4 oacc[4];
#pragma unroll
    for (int v4 = 0; v4 < 4; ++v4) oacc[v4] = (f32x4){0.f, 0.f, 0.f, 0.f};
    float lr[4];
#pragma unroll
    for (int r = 0; r < 4; ++r) lr[r] = 1.f;   // sink: exp(0)

    for (int c = 0; c < 5; ++c) {
        const int kb = q0 - 256 + c * 64;
        if (kb < 0) continue;
        __syncthreads();

        // stage K [64][64] and V^T [64][64], b128 copies
#pragma unroll
        for (int i = 0; i < 2; ++i) {
            const int id  = t + 256 * i;
            const int row = id >> 3;
            const int co  = (id & 7) * 8;
            *(bf16x8*)&Ks[row * KP + co] =
                *(const bf16x8*)(k + zbase + (size_t)(kb + row) * DHEAD + co);
            *(bf16x8*)&Vs[row * KP + co] =
                *(const bf16x8*)(vt + ((size_t)z * DHEAD + row) * S_LEN + kb + co);
        }
        __syncthreads();

        // S = Q K^T
        f32x4 sacc[4];
#pragma unroll
        for (int v4 = 0; v4 < 4; ++v4) {
            sacc[v4] = (f32x4){0.f, 0.f, 0.f, 0.f};
            bf16x8 kf0 = *(const bf16x8*)&Ks[(v4 * 16 + m16) * KP + g * 8];
            sacc[v4] = __builtin_amdgcn_mfma_f32_16x16x32_bf16(qf0, kf0, sacc[v4], 0, 0, 0);
            bf16x8 kf1 = *(const bf16x8*)&Ks[(v4 * 16 + m16) * KP + 32 + g * 8];
            sacc[v4] = __builtin_amdgcn_mfma_f32_16x16x32_bf16(qf1, kf1, sacc[v4], 0, 0, 0);
        }

        // mask + exp + row-sum (no max): P -> LDS
        const bool mhi = (c == 4), mlo = (c == 0);
#pragma unroll
        for (int r = 0; r < 4; ++r) {
            const int ig = q0 + wv * 16 + g * 4 + r;
            float rsum = 0.f;
#pragma unroll
            for (int v4 = 0; v4 < 4; ++v4) {
                const int jg = kb + v4 * 16 + m16;
                float x = sacc[v4][r];
                const bool valid = (!mhi || jg <= ig) && (!mlo || jg >= ig - (WIN - 1));
                x = valid ? x : -1e30f;
                const float pp = __expf(x);     // masked -> exactly 0
                Ps[wv * 16 + g * 4 + r][v4 * 16 + m16] = pp;
                rsum += pp;
            }
#pragma unroll
            for (int off = 1; off < 16; off <<= 1)
                rsum += __shfl_xor(rsum, off, 64);
            lr[r] += rsum;
        }
        __syncthreads();

        // O += P V
        const float* prow = &Ps[wv * 16 + m16][0];
        bf16x8 pf0 = pack8(*(const float4*)(prow + g * 8),
                           *(const float4*)(prow + g * 8 + 4));
        bf16x8 pf1 = pack8(*(const float4*)(prow + 32 + g * 8),
                           *(const float4*)(prow + 32 + g * 8 + 4));
#pragma unroll
        for (int v4 = 0; v4 < 4; ++v4) {
            bf16x8 vf0 = *(const bf16x8*)&Vs[(v4 * 16 + m16) * KP + g * 8];
            oacc[v4] = __builtin_amdgcn_mfma_f32_16x16x32_bf16(pf0, vf0, oacc[v4], 0, 0, 0);
            bf16x8 vf1 = *(const bf16x8*)&Vs[(v4 * 16 + m16) * KP + 32 + g * 8];
            oacc[v4] = __builtin_amdgcn_mfma_f32_16x16x32_bf16(pf1, vf1, oacc[v4], 0, 0, 0);
        }
    }

    const int bb = z >> 4, h = z & 15;
#pragma unroll
    for (int r = 0; r < 4; ++r) {
        const int ig  = q0 + wv * 16 + g * 4 + r;
        const float inv = 1.f / lr[r];
#pragma unroll
        for (int v4 = 0; v4 < 4; ++v4)
            ao[(size_t)(ig * BATCH + bb) * DM + h * DHEAD + v4 * 16 + m16] =
                f2b(oacc[v4][r] * inv);
    }
}

// ---------------------------------------------------------------------------
extern "C" void kernel_launch(void* const* d_in, const int* in_sizes, int n_in,
                              void* d_out, int out_size, void* d_ws, size_t ws_size,
                              hipStream_t stream)
{
    const float* x    = (const float*)d_in[0];
    const float* beta = (const float*)d_in[1];
    const float* Wq   = (const float*)d_in[2];
    const float* bq   = (const float*)d_in[3];
    const float* Wk   = (const float*)d_in[4];
    const float* bk   = (const float*)d_in[5];
    const float* Wv   = (const float*)d_in[6];
    const float* bv   = (const float*)d_in[7];
    const float* Wo   = (const float*)d_in[8];
    const float* bo   = (const float*)d_in[9];
    float* out = (float*)d_out;

    unsigned short* w = (unsigned short*)d_ws;
    const size_t seg = (size_t)MROWS * DM;      // 4M elems
    unsigned short* qb  = w;                    // q (z,s,dh)
    unsigned short* kb  = w + seg;              // k (z,s,dh)
    unsigned short* vtb = w + 2 * seg;          // v^T (z,dh,s) -- direct from QKV
    unsigned short* ab  = w + 3 * seg;          // attn out, row-major
    unsigned short* xb  = w + 4 * seg;          // x bf16
    unsigned short* wtq = w + 5 * seg;          // WqT|WkT|WvT|WoT contiguous
    unsigned short* wtk = wtq + (size_t)DM * DM;
    unsigned short* wtv = wtk + (size_t)DM * DM;
    unsigned short* wto = wtv + (size_t)DM * DM;

    cvtx<<<4096, 256, 0, stream>>>(x, xb);
    twcvt4<<<dim3(32, 32, 4), 256, 0, stream>>>(Wq, Wk, Wv, Wo, wtq, wtk, wtv, wto);

    // fused Q+K+V projection: N=3072, V written pre-transposed (768 blocks)
    gemm_qkv<<<dim3(3072 / 128, MROWS / 128), 256, 0, stream>>>(
        xb, wtq, bq, bk, bv, beta, qb);

    attn_mfma<<<dim3(S_LEN / 64, BATCH * NHEAD), 256, 0, stream>>>(qb, kb, vtb, ab);

    // output projection: 128x64 tiles -> 512 blocks (2/CU)
    gemm_out<<<dim3(DM / 64, MROWS / 128), 256, 0, stream>>>(ab, wto, bo, out);
}